// Round 1
// baseline (412.661 us; speedup 1.0000x reference)
//
#include <hip/hip_runtime.h>

#define HEADS 4
#define NH    256     // h dimension
#define LEN   4096    // sequence length
#define NB    16      // batch
#define NTAP  192     // 6 scales * 32 taps
#define TTILE 512
#define HALO  1024
#define XS_N  (TTILE + HALO)   // 1536

// ---------------------------------------------------------------------------
// Build compressed, normalized weights.
// k[c,h,p] is kernels[i,c,h,j] * 2^(5-i) repeated rep_i = 2^max(0,i-1) times,
// normalized by ||k[c,h,:]||_2.  We store only the 192 distinct weights per
// (h), packed as float4 over c:  wgt4[h*192 + tap].
// ---------------------------------------------------------------------------
__global__ __launch_bounds__(64) void build_wgt_kernel(
    const float* __restrict__ kernels, float4* __restrict__ wgt4)
{
    const int h    = blockIdx.x;
    const int lane = threadIdx.x;   // 64 lanes, 3 taps each

    float vals[3][4];
    float ssum[4] = {0.f, 0.f, 0.f, 0.f};

    #pragma unroll
    for (int q = 0; q < 3; ++q) {
        const int tap = lane + q * 64;
        const int i = tap >> 5;      // scale
        const int j = tap & 31;      // base tap
        const float scale = (float)(1 << (5 - i));            // 2^(5-i)
        const float repf  = (float)(i == 0 ? 1 : (1 << (i - 1)));
        #pragma unroll
        for (int c = 0; c < 4; ++c) {
            const float kv = kernels[(((i * HEADS) + c) * NH + h) * 32 + j];
            const float v  = kv * scale;
            vals[q][c] = v;
            ssum[c]   += v * v * repf;   // repeated taps count rep times
        }
    }

    // wave64 butterfly reduction -> every lane holds the 4 norms
    #pragma unroll
    for (int off = 32; off > 0; off >>= 1) {
        #pragma unroll
        for (int c = 0; c < 4; ++c) ssum[c] += __shfl_xor(ssum[c], off);
    }

    float inv[4];
    #pragma unroll
    for (int c = 0; c < 4; ++c) inv[c] = 1.0f / sqrtf(ssum[c]);

    #pragma unroll
    for (int q = 0; q < 3; ++q) {
        const int tap = lane + q * 64;
        wgt4[h * NTAP + tap] = make_float4(vals[q][0] * inv[0],
                                           vals[q][1] * inv[1],
                                           vals[q][2] * inv[2],
                                           vals[q][3] * inv[3]);
    }
}

// ---------------------------------------------------------------------------
// Main conv kernel.  Grid: (8 t-tiles, 256 h, 16 b), 256 threads.
// y[t] = sum_i sum_j w_i[j] * W_{rep_i}[t + 512 - P_i - j*rep_i]
// where W_r[m] = sum_{q<r} x[m-q]  (windowed sums, built in LDS by doubling).
// Local coords: l = global_index - (t0 - 512), arrays sized 1536.
// ---------------------------------------------------------------------------
__global__ __launch_bounds__(256) void conv_kernel(
    const float*  __restrict__ x,
    const float4* __restrict__ wgt4,
    const float*  __restrict__ D,
    float*        __restrict__ out)
{
    __shared__ float  xs [XS_N];
    __shared__ float  W2 [XS_N];
    __shared__ float  W4 [XS_N];
    __shared__ float  W8 [XS_N];
    __shared__ float  W16[XS_N];
    __shared__ float4 wl [NTAP];

    const int tile = blockIdx.x;
    const int h    = blockIdx.y;
    const int b    = blockIdx.z;
    const int tid  = threadIdx.x;
    const int t0   = tile * TTILE;

    const float* xrow = x + ((size_t)(b * NH + h)) * LEN;

    // stage x with halo, zero-padded outside [0, LEN)
    #pragma unroll
    for (int q = 0; q < XS_N / 256; ++q) {
        const int m = tid + q * 256;
        const int g = t0 - 512 + m;
        xs[m] = (g >= 0 && g < LEN) ? xrow[g] : 0.f;
    }
    if (tid < NTAP) wl[tid] = wgt4[h * NTAP + tid];
    __syncthreads();

    #pragma unroll
    for (int q = 0; q < XS_N / 256; ++q) {
        const int m = tid + q * 256;
        W2[m] = (m >= 1) ? xs[m] + xs[m - 1] : 0.f;
    }
    __syncthreads();
    #pragma unroll
    for (int q = 0; q < XS_N / 256; ++q) {
        const int m = tid + q * 256;
        W4[m] = (m >= 2) ? W2[m] + W2[m - 2] : 0.f;
    }
    __syncthreads();
    #pragma unroll
    for (int q = 0; q < XS_N / 256; ++q) {
        const int m = tid + q * 256;
        W8[m] = (m >= 4) ? W4[m] + W4[m - 4] : 0.f;
    }
    __syncthreads();
    #pragma unroll
    for (int q = 0; q < XS_N / 256; ++q) {
        const int m = tid + q * 256;
        W16[m] = (m >= 8) ? W8[m] + W8[m - 8] : 0.f;
    }
    __syncthreads();

    const int u0 = tid;
    const int u1 = tid + 256;

    float acc0[4] = {0.f, 0.f, 0.f, 0.f};
    float acc1[4] = {0.f, 0.f, 0.f, 0.f};

    // BASE_i = 1024 - P_i ; taps at l = u + BASE_i - j*rep_i
#define SCALE_LOOP(WARR, TAPBASE, BASE, R)                                   \
    {                                                                        \
        _Pragma("unroll")                                                    \
        for (int j = 0; j < 32; ++j) {                                       \
            const float4 w   = wl[(TAPBASE) + j];                            \
            const float  wv0 = WARR[u0 + (BASE) - j * (R)];                  \
            const float  wv1 = WARR[u1 + (BASE) - j * (R)];                  \
            acc0[0] += w.x * wv0; acc0[1] += w.y * wv0;                      \
            acc0[2] += w.z * wv0; acc0[3] += w.w * wv0;                      \
            acc1[0] += w.x * wv1; acc1[1] += w.y * wv1;                      \
            acc1[2] += w.z * wv1; acc1[3] += w.w * wv1;                      \
        }                                                                    \
    }

    SCALE_LOOP(xs,  0,   1024, 1)    // scale 0, rep 1
    SCALE_LOOP(xs,  32,  992,  1)    // scale 1, rep 1
    SCALE_LOOP(W2,  64,  960,  2)    // scale 2, rep 2
    SCALE_LOOP(W4,  96,  896,  4)    // scale 3, rep 4
    SCALE_LOOP(W8,  128, 768,  8)    // scale 4, rep 8
    SCALE_LOOP(W16, 160, 512,  16)   // scale 5, rep 16
#undef SCALE_LOOP

    // skip connection + store
    const float xv0 = xs[u0 + 512];
    const float xv1 = xs[u1 + 512];
    const size_t obase = (size_t)b * (NH * HEADS) + (size_t)h * HEADS;

    #pragma unroll
    for (int c = 0; c < 4; ++c) {
        const float d = D[c * NH + h];
        out[(obase + c) * LEN + t0 + u0] = acc0[c] + xv0 * d;
        out[(obase + c) * LEN + t0 + u1] = acc1[c] + xv1 * d;
    }
}

extern "C" void kernel_launch(void* const* d_in, const int* in_sizes, int n_in,
                              void* d_out, int out_size, void* d_ws, size_t ws_size,
                              hipStream_t stream)
{
    const float* x       = (const float*)d_in[0];
    const float* kernels = (const float*)d_in[1];
    const float* D       = (const float*)d_in[2];
    float*       out     = (float*)d_out;
    float4*      wgt4    = (float4*)d_ws;   // 256*192*16 B = 768 KiB

    build_wgt_kernel<<<256, 64, 0, stream>>>(kernels, wgt4);
    conv_kernel<<<dim3(8, NH, NB), 256, 0, stream>>>(x, wgt4, D, out);
}

// Round 2
// 320.478 us; speedup vs baseline: 1.2876x; 1.2876x over previous
//
#include <hip/hip_runtime.h>

#define HEADS 4
#define NH    256
#define LEN   4096
#define NB    16
#define NTAP  192
#define TT    1024          // t-tile per block
#define XS_N  2048          // TT + 1024 halo (512 left, 512 right)

typedef float f32x4 __attribute__((ext_vector_type(4)));
typedef float f32x2 __attribute__((ext_vector_type(2)));

// ---------------------------------------------------------------------------
// Build compressed, normalized weights (unchanged from R1 — verified).
// wgt4[h*192 + tap] packs the 4 heads' weights as float4.
// ---------------------------------------------------------------------------
__global__ __launch_bounds__(64) void build_wgt_kernel(
    const float* __restrict__ kernels, float4* __restrict__ wgt4)
{
    const int h    = blockIdx.x;
    const int lane = threadIdx.x;

    float vals[3][4];
    float ssum[4] = {0.f, 0.f, 0.f, 0.f};

    #pragma unroll
    for (int q = 0; q < 3; ++q) {
        const int tap = lane + q * 64;
        const int i = tap >> 5;
        const int j = tap & 31;
        const float scale = (float)(1 << (5 - i));
        const float repf  = (float)(i == 0 ? 1 : (1 << (i - 1)));
        #pragma unroll
        for (int c = 0; c < 4; ++c) {
            const float kv = kernels[(((i * HEADS) + c) * NH + h) * 32 + j];
            const float v  = kv * scale;
            vals[q][c] = v;
            ssum[c]   += v * v * repf;
        }
    }
    #pragma unroll
    for (int off = 32; off > 0; off >>= 1) {
        #pragma unroll
        for (int c = 0; c < 4; ++c) ssum[c] += __shfl_xor(ssum[c], off);
    }
    float inv[4];
    #pragma unroll
    for (int c = 0; c < 4; ++c) inv[c] = 1.0f / sqrtf(ssum[c]);
    #pragma unroll
    for (int q = 0; q < 3; ++q) {
        const int tap = lane + q * 64;
        wgt4[h * NTAP + tap] = make_float4(vals[q][0] * inv[0],
                                           vals[q][1] * inv[1],
                                           vals[q][2] * inv[2],
                                           vals[q][3] * inv[3]);
    }
}

// ---------------------------------------------------------------------------
// Main conv kernel.  Grid: (4 t-tiles, 256 h, 16 b), 256 threads.
// Thread handles 4 CONSECUTIVE t (u = 4*tid + delta), 4 heads, via packed-f32
// FMAs (acc paired over heads) and aligned ds_read_b128 sliding windows.
// ---------------------------------------------------------------------------
__global__ __launch_bounds__(256) void conv_kernel(
    const float*  __restrict__ x,
    const float4* __restrict__ wgt4,
    const float*  __restrict__ D,
    float*        __restrict__ out)
{
    __shared__ __align__(16) float xs [XS_N];
    __shared__ __align__(16) float W2 [XS_N];
    __shared__ __align__(16) float W4 [XS_N];
    __shared__ __align__(16) float W8 [XS_N];
    __shared__ __align__(16) float W16[XS_N];
    __shared__ __align__(16) f32x4 wl [NTAP];

    const int tile = blockIdx.x;
    const int h    = blockIdx.y;
    const int b    = blockIdx.z;
    const int tid  = threadIdx.x;
    const int t0   = tile * TT;

    const float* xrow = x + ((size_t)(b * NH + h)) * LEN;

    // ---- stage x with halo (zero-padded) ----
    #pragma unroll
    for (int q = 0; q < XS_N / 256; ++q) {
        const int m = tid + q * 256;
        const int g = t0 - 512 + m;
        xs[m] = (g >= 0 && g < LEN) ? xrow[g] : 0.f;
    }
    if (tid < NTAP) wl[tid] = *reinterpret_cast<const f32x4*>(&wgt4[h * NTAP + tid]);
    __syncthreads();

    // ---- window-sum arrays by doubling ----
    #pragma unroll
    for (int q = 0; q < XS_N / 256; ++q) {
        const int m = tid + q * 256;
        W2[m] = (m >= 1) ? xs[m] + xs[m - 1] : 0.f;
    }
    __syncthreads();
    #pragma unroll
    for (int q = 0; q < XS_N / 256; ++q) {
        const int m = tid + q * 256;
        W4[m] = (m >= 2) ? W2[m] + W2[m - 2] : 0.f;
    }
    __syncthreads();
    #pragma unroll
    for (int q = 0; q < XS_N / 256; ++q) {
        const int m = tid + q * 256;
        W8[m] = (m >= 4) ? W4[m] + W4[m - 4] : 0.f;
    }
    __syncthreads();
    #pragma unroll
    for (int q = 0; q < XS_N / 256; ++q) {
        const int m = tid + q * 256;
        W16[m] = (m >= 8) ? W8[m] + W8[m - 8] : 0.f;
    }
    __syncthreads();

    const int A = 4 * tid;          // local t-base of this thread

#define LD4(ARR, IDX) (*reinterpret_cast<const f32x4*>(&(ARR)[(IDX)]))

    // accumulators: a01[delta] = (c0,c1), a23[delta] = (c2,c3)
    f32x2 a01[4], a23[4];
    #pragma unroll
    for (int d = 0; d < 4; ++d) { a01[d] = (f32x2){0.f, 0.f}; a23[d] = (f32x2){0.f, 0.f}; }

#define TAP8(W, V0, V1, V2, V3) do {                                          \
        const f32x2 _wa = (W).xy, _wb = (W).zw;                               \
        a01[0] = __builtin_elementwise_fma(_wa, (f32x2){(V0),(V0)}, a01[0]);  \
        a23[0] = __builtin_elementwise_fma(_wb, (f32x2){(V0),(V0)}, a23[0]);  \
        a01[1] = __builtin_elementwise_fma(_wa, (f32x2){(V1),(V1)}, a01[1]);  \
        a23[1] = __builtin_elementwise_fma(_wb, (f32x2){(V1),(V1)}, a23[1]);  \
        a01[2] = __builtin_elementwise_fma(_wa, (f32x2){(V2),(V2)}, a01[2]);  \
        a23[2] = __builtin_elementwise_fma(_wb, (f32x2){(V2),(V2)}, a23[2]);  \
        a01[3] = __builtin_elementwise_fma(_wa, (f32x2){(V3),(V3)}, a01[3]);  \
        a23[3] = __builtin_elementwise_fma(_wb, (f32x2){(V3),(V3)}, a23[3]);  \
    } while (0)

    // ---- scales 0+1 : xs, rep 1, 64 taps, weights wl[0..63], base A+1024 ----
    {
        const int A0 = A + 1024;
        f32x4 hi = LD4(xs, A0);
        #pragma unroll 2
        for (int g = 0; g < 16; ++g) {
            const f32x4 lo = LD4(xs, A0 - 4 * g - 4);
            f32x4 w;
            w = wl[4 * g + 0]; TAP8(w, hi.x, hi.y, hi.z, hi.w);
            w = wl[4 * g + 1]; TAP8(w, lo.w, hi.x, hi.y, hi.z);
            w = wl[4 * g + 2]; TAP8(w, lo.z, lo.w, hi.x, hi.y);
            w = wl[4 * g + 3]; TAP8(w, lo.y, lo.z, lo.w, hi.x);
            hi = lo;
        }
    }
    // ---- scale 2 : W2, rep 2, base A+960, weights wl[64..95] ----
    {
        const int A2 = A + 960;
        f32x4 hi = LD4(W2, A2);
        #pragma unroll 2
        for (int g = 0; g < 16; ++g) {
            const f32x4 lo = LD4(W2, A2 - 4 * g - 4);
            f32x4 w;
            w = wl[64 + 2 * g + 0]; TAP8(w, hi.x, hi.y, hi.z, hi.w);
            w = wl[64 + 2 * g + 1]; TAP8(w, lo.z, lo.w, hi.x, hi.y);
            hi = lo;
        }
    }
    // ---- scale 3 : W4, rep 4, base A+896, weights wl[96..127] ----
    {
        const int A3 = A + 896;
        #pragma unroll 4
        for (int j = 0; j < 32; ++j) {
            const f32x4 v = LD4(W4, A3 - 4 * j);
            const f32x4 w = wl[96 + j];
            TAP8(w, v.x, v.y, v.z, v.w);
        }
    }
    // ---- scale 4 : W8, rep 8, base A+768, weights wl[128..159] ----
    {
        const int A4 = A + 768;
        #pragma unroll 4
        for (int j = 0; j < 32; ++j) {
            const f32x4 v = LD4(W8, A4 - 8 * j);
            const f32x4 w = wl[128 + j];
            TAP8(w, v.x, v.y, v.z, v.w);
        }
    }
    // ---- scale 5 : W16, rep 16, base A+512, weights wl[160..191] ----
    {
        const int A5 = A + 512;
        #pragma unroll 4
        for (int j = 0; j < 32; ++j) {
            const f32x4 v = LD4(W16, A5 - 16 * j);
            const f32x4 w = wl[160 + j];
            TAP8(w, v.x, v.y, v.z, v.w);
        }
    }
#undef TAP8

    // ---- skip connection + store (float4, coalesced) ----
    const f32x4 xv = LD4(xs, A + 512);
    const float d0 = D[0 * NH + h];
    const float d1 = D[1 * NH + h];
    const float d2 = D[2 * NH + h];
    const float d3 = D[3 * NH + h];

    const size_t obase = ((size_t)b * (NH * HEADS) + (size_t)h * HEADS) * LEN
                       + (size_t)t0 + (size_t)A;

    f32x4 o;
    o = (f32x4){a01[0].x, a01[1].x, a01[2].x, a01[3].x};
    o += xv * d0;
    *reinterpret_cast<f32x4*>(out + obase + 0 * LEN) = o;
    o = (f32x4){a01[0].y, a01[1].y, a01[2].y, a01[3].y};
    o += xv * d1;
    *reinterpret_cast<f32x4*>(out + obase + 1 * LEN) = o;
    o = (f32x4){a23[0].x, a23[1].x, a23[2].x, a23[3].x};
    o += xv * d2;
    *reinterpret_cast<f32x4*>(out + obase + 2 * LEN) = o;
    o = (f32x4){a23[0].y, a23[1].y, a23[2].y, a23[3].y};
    o += xv * d3;
    *reinterpret_cast<f32x4*>(out + obase + 3 * LEN) = o;
#undef LD4
}

extern "C" void kernel_launch(void* const* d_in, const int* in_sizes, int n_in,
                              void* d_out, int out_size, void* d_ws, size_t ws_size,
                              hipStream_t stream)
{
    const float* x       = (const float*)d_in[0];
    const float* kernels = (const float*)d_in[1];
    const float* D       = (const float*)d_in[2];
    float*       out     = (float*)d_out;
    float4*      wgt4    = (float4*)d_ws;   // 768 KiB

    build_wgt_kernel<<<256, 64, 0, stream>>>(kernels, wgt4);
    conv_kernel<<<dim3(LEN / TT, NH, NB), 256, 0, stream>>>(x, wgt4, D, out);
}

// Round 3
// 283.991 us; speedup vs baseline: 1.4531x; 1.1285x over previous
//
#include <hip/hip_runtime.h>

#define HEADS 4
#define NH    256
#define LEN   4096
#define NB    16
#define NTAP  192
#define TT    1024          // t-tile per block
#define XS_N  2048          // TT + 1024 halo (512 left, 512 right)

typedef float f32x4 __attribute__((ext_vector_type(4)));
typedef float f32x2 __attribute__((ext_vector_type(2)));

// ---------------------------------------------------------------------------
// Build compressed, normalized weights (verified in R1/R2).
// wgt4[h*192 + tap] packs the 4 heads' weights as float4 = (c0,c1,c2,c3).
// ---------------------------------------------------------------------------
__global__ __launch_bounds__(64) void build_wgt_kernel(
    const float* __restrict__ kernels, float4* __restrict__ wgt4)
{
    const int h    = blockIdx.x;
    const int lane = threadIdx.x;

    float vals[3][4];
    float ssum[4] = {0.f, 0.f, 0.f, 0.f};

    #pragma unroll
    for (int q = 0; q < 3; ++q) {
        const int tap = lane + q * 64;
        const int i = tap >> 5;
        const int j = tap & 31;
        const float scale = (float)(1 << (5 - i));
        const float repf  = (float)(i == 0 ? 1 : (1 << (i - 1)));
        #pragma unroll
        for (int c = 0; c < 4; ++c) {
            const float kv = kernels[(((i * HEADS) + c) * NH + h) * 32 + j];
            const float v  = kv * scale;
            vals[q][c] = v;
            ssum[c]   += v * v * repf;
        }
    }
    #pragma unroll
    for (int off = 32; off > 0; off >>= 1) {
        #pragma unroll
        for (int c = 0; c < 4; ++c) ssum[c] += __shfl_xor(ssum[c], off);
    }
    float inv[4];
    #pragma unroll
    for (int c = 0; c < 4; ++c) inv[c] = 1.0f / sqrtf(ssum[c]);
    #pragma unroll
    for (int q = 0; q < 3; ++q) {
        const int tap = lane + q * 64;
        wgt4[h * NTAP + tap] = make_float4(vals[q][0] * inv[0],
                                           vals[q][1] * inv[1],
                                           vals[q][2] * inv[2],
                                           vals[q][3] * inv[3]);
    }
}

// ---------------------------------------------------------------------------
// Main conv kernel.  Grid: (4 t-tiles, 256 h, 16 b), 256 threads.
// Weights: block-uniform global loads -> SGPR quads (no LDS).
// FMAs: v_pk_fma_f32, acc pairs over heads, value splat via op_sel.
// ---------------------------------------------------------------------------

// acc += (w0,w1) * splat(vp.lo)
#define PK_LO(ACC, W, VP) \
    asm("v_pk_fma_f32 %0, %1, %2, %0 op_sel:[0,0,0] op_sel_hi:[1,0,1]" \
        : "+v"(ACC) : "s"(W), "v"(VP))
// acc += (w0,w1) * splat(vp.hi)
#define PK_HI(ACC, W, VP) \
    asm("v_pk_fma_f32 %0, %1, %2, %0 op_sel:[0,1,0] op_sel_hi:[1,1,1]" \
        : "+v"(ACC) : "s"(W), "v"(VP))

__global__ __launch_bounds__(256) void conv_kernel(
    const float*  __restrict__ x,
    const f32x4*  __restrict__ wgt4,
    const float*  __restrict__ D,
    float*        __restrict__ out)
{
    __shared__ __align__(16) float xs [XS_N];
    __shared__ __align__(16) float W2 [XS_N];
    __shared__ __align__(16) float W4 [XS_N];
    __shared__ __align__(16) float W8 [XS_N];
    __shared__ __align__(16) float W16[XS_N];

    const int tile = blockIdx.x;
    const int h    = blockIdx.y;
    const int b    = blockIdx.z;
    const int tid  = threadIdx.x;
    const int t0   = tile * TT;

    const float* xrow = x + ((size_t)(b * NH + h)) * LEN;
    const f32x4* wrow = wgt4 + (size_t)h * NTAP;   // block-uniform -> s_load

    // ---- stage x with halo (zero-padded) ----
    #pragma unroll
    for (int q = 0; q < XS_N / 256; ++q) {
        const int m = tid + q * 256;
        const int g = t0 - 512 + m;
        xs[m] = (g >= 0 && g < LEN) ? xrow[g] : 0.f;
    }
    __syncthreads();

    // ---- window-sum arrays by doubling ----
    #pragma unroll
    for (int q = 0; q < XS_N / 256; ++q) {
        const int m = tid + q * 256;
        W2[m] = (m >= 1) ? xs[m] + xs[m - 1] : 0.f;
    }
    __syncthreads();
    #pragma unroll
    for (int q = 0; q < XS_N / 256; ++q) {
        const int m = tid + q * 256;
        W4[m] = (m >= 2) ? W2[m] + W2[m - 2] : 0.f;
    }
    __syncthreads();
    #pragma unroll
    for (int q = 0; q < XS_N / 256; ++q) {
        const int m = tid + q * 256;
        W8[m] = (m >= 4) ? W4[m] + W4[m - 4] : 0.f;
    }
    __syncthreads();
    #pragma unroll
    for (int q = 0; q < XS_N / 256; ++q) {
        const int m = tid + q * 256;
        W16[m] = (m >= 8) ? W8[m] + W8[m - 8] : 0.f;
    }
    __syncthreads();

    const int A = 4 * tid;

#define LD4(ARR, IDX) (*reinterpret_cast<const f32x4*>(&(ARR)[(IDX)]))

    // accumulators: a01[delta]=(c0,c1), a23[delta]=(c2,c3)
    f32x2 a01[4], a23[4];
    #pragma unroll
    for (int d = 0; d < 4; ++d) { a01[d] = (f32x2){0.f, 0.f}; a23[d] = (f32x2){0.f, 0.f}; }

    // TAP: weight quad W (SGPRs), per-delta (containing pair, LO/HI selector)
#define TAP(W, P0,S0, P1,S1, P2,S2, P3,S3) do {                    \
        const f32x2 _w01 = (W).xy, _w23 = (W).zw;                  \
        const f32x2 _p0 = (P0), _p1 = (P1), _p2 = (P2), _p3 = (P3);\
        PK_##S0(a01[0], _w01, _p0); PK_##S0(a23[0], _w23, _p0);    \
        PK_##S1(a01[1], _w01, _p1); PK_##S1(a23[1], _w23, _p1);    \
        PK_##S2(a01[2], _w01, _p2); PK_##S2(a23[2], _w23, _p2);    \
        PK_##S3(a01[3], _w01, _p3); PK_##S3(a23[3], _w23, _p3);    \
    } while (0)

    // ---- scales 0+1 : xs, rep 1, 64 taps, base A+1024 ----
    {
        const int A0 = A + 1024;
        f32x4 hi = LD4(xs, A0);
        #pragma unroll 4
        for (int g = 0; g < 16; ++g) {
            const f32x4 lo = LD4(xs, A0 - 4 * g - 4);
            f32x4 w;
            w = wrow[4 * g + 0]; TAP(w, hi.xy,LO, hi.xy,HI, hi.zw,LO, hi.zw,HI);
            w = wrow[4 * g + 1]; TAP(w, lo.zw,HI, hi.xy,LO, hi.xy,HI, hi.zw,LO);
            w = wrow[4 * g + 2]; TAP(w, lo.zw,LO, lo.zw,HI, hi.xy,LO, hi.xy,HI);
            w = wrow[4 * g + 3]; TAP(w, lo.xy,HI, lo.zw,LO, lo.zw,HI, hi.xy,LO);
            hi = lo;
        }
    }
    // ---- scale 2 : W2, rep 2, base A+960, weights 64..95 ----
    {
        const int A2 = A + 960;
        f32x4 hi = LD4(W2, A2);
        #pragma unroll 4
        for (int g = 0; g < 16; ++g) {
            const f32x4 lo = LD4(W2, A2 - 4 * g - 4);
            f32x4 w;
            w = wrow[64 + 2 * g + 0]; TAP(w, hi.xy,LO, hi.xy,HI, hi.zw,LO, hi.zw,HI);
            w = wrow[64 + 2 * g + 1]; TAP(w, lo.zw,LO, lo.zw,HI, hi.xy,LO, hi.xy,HI);
            hi = lo;
        }
    }
    // ---- scale 3 : W4, rep 4, base A+896, weights 96..127 ----
    {
        const int A3 = A + 896;
        #pragma unroll 4
        for (int j = 0; j < 32; ++j) {
            const f32x4 v = LD4(W4, A3 - 4 * j);
            const f32x4 w = wrow[96 + j];
            TAP(w, v.xy,LO, v.xy,HI, v.zw,LO, v.zw,HI);
        }
    }
    // ---- scale 4 : W8, rep 8, base A+768, weights 128..159 ----
    {
        const int A4 = A + 768;
        #pragma unroll 4
        for (int j = 0; j < 32; ++j) {
            const f32x4 v = LD4(W8, A4 - 8 * j);
            const f32x4 w = wrow[128 + j];
            TAP(w, v.xy,LO, v.xy,HI, v.zw,LO, v.zw,HI);
        }
    }
    // ---- scale 5 : W16, rep 16, base A+512, weights 160..191 ----
    {
        const int A5 = A + 512;
        #pragma unroll 4
        for (int j = 0; j < 32; ++j) {
            const f32x4 v = LD4(W16, A5 - 16 * j);
            const f32x4 w = wrow[160 + j];
            TAP(w, v.xy,LO, v.xy,HI, v.zw,LO, v.zw,HI);
        }
    }
#undef TAP

    // ---- skip connection + store (float4, coalesced) ----
    const f32x4 xv = LD4(xs, A + 512);
    const float d0 = D[0 * NH + h];
    const float d1 = D[1 * NH + h];
    const float d2 = D[2 * NH + h];
    const float d3 = D[3 * NH + h];

    const size_t obase = ((size_t)b * (NH * HEADS) + (size_t)h * HEADS) * LEN
                       + (size_t)t0 + (size_t)A;

    f32x4 o;
    o = (f32x4){a01[0].x, a01[1].x, a01[2].x, a01[3].x};
    o += xv * d0;
    *reinterpret_cast<f32x4*>(out + obase + 0 * LEN) = o;
    o = (f32x4){a01[0].y, a01[1].y, a01[2].y, a01[3].y};
    o += xv * d1;
    *reinterpret_cast<f32x4*>(out + obase + 1 * LEN) = o;
    o = (f32x4){a23[0].x, a23[1].x, a23[2].x, a23[3].x};
    o += xv * d2;
    *reinterpret_cast<f32x4*>(out + obase + 2 * LEN) = o;
    o = (f32x4){a23[0].y, a23[1].y, a23[2].y, a23[3].y};
    o += xv * d3;
    *reinterpret_cast<f32x4*>(out + obase + 3 * LEN) = o;
#undef LD4
}

extern "C" void kernel_launch(void* const* d_in, const int* in_sizes, int n_in,
                              void* d_out, int out_size, void* d_ws, size_t ws_size,
                              hipStream_t stream)
{
    const float* x       = (const float*)d_in[0];
    const float* kernels = (const float*)d_in[1];
    const float* D       = (const float*)d_in[2];
    float*       out     = (float*)d_out;
    float4*      wgt4    = (float4*)d_ws;   // 768 KiB

    build_wgt_kernel<<<256, 64, 0, stream>>>(kernels, wgt4);
    conv_kernel<<<dim3(LEN / TT, NH, NB), 256, 0, stream>>>(
        x, (const f32x4*)wgt4, D, out);
}

// Round 6
// 258.765 us; speedup vs baseline: 1.5947x; 1.0975x over previous
//
#include <hip/hip_runtime.h>

#define HEADS 4
#define NH    256
#define LEN   4096
#define NB    16
#define TT    1024
#define NPAIR 96            // 6 scales * 16 tap-pairs

typedef float     f32x4 __attribute__((ext_vector_type(4)));
typedef _Float16  f16x2 __attribute__((ext_vector_type(2)));
typedef unsigned  u32x2 __attribute__((ext_vector_type(2)));
typedef unsigned  u32x4 __attribute__((ext_vector_type(4)));

// pack two floats to f16 pair; a -> bits[15:0], b -> bits[31:16].
__device__ __forceinline__ unsigned packh(float a, float b) {
    union { _Float16 h[2]; unsigned u; } z;
    z.h[0] = (_Float16)a;
    z.h[1] = (_Float16)b;
    return z.u;
}

// ---------------------------------------------------------------------------
// Weight table: per h, 96 pair-entries (u32x4 over 4 heads), each dword =
// packed f16 (w[2p] in bits[15:0], w[2p+1] in bits[31:16]), normalized.
// ---------------------------------------------------------------------------
__global__ __launch_bounds__(64) void build_wgt_kernel(
    const float* __restrict__ kernels, u32x4* __restrict__ wtab)
{
    const int h    = blockIdx.x;
    const int lane = threadIdx.x;

    float ssum[4] = {0.f, 0.f, 0.f, 0.f};
    #pragma unroll
    for (int q = 0; q < 3; ++q) {
        const int tap = lane + q * 64;
        const int i = tap >> 5;
        const int j = tap & 31;
        const float scale = (float)(1 << (5 - i));
        const float repf  = (float)(i == 0 ? 1 : (1 << (i - 1)));
        #pragma unroll
        for (int c = 0; c < 4; ++c) {
            const float kv = kernels[(((i * HEADS) + c) * NH + h) * 32 + j];
            const float v  = kv * scale;
            ssum[c] += v * v * repf;
        }
    }
    #pragma unroll
    for (int off = 32; off > 0; off >>= 1) {
        #pragma unroll
        for (int c = 0; c < 4; ++c) ssum[c] += __shfl_xor(ssum[c], off);
    }
    float inv[4];
    #pragma unroll
    for (int c = 0; c < 4; ++c) inv[c] = 1.0f / sqrtf(ssum[c]);

    #pragma unroll
    for (int it = 0; it < 2; ++it) {
        const int pp = lane + 64 * it;      // pair index
        if (pp < NPAIR) {
            const int s = pp >> 4;          // 16 pairs per scale
            const int p = pp & 15;
            const float sc = (float)(1 << (5 - s));
            u32x4 o;
            #pragma unroll
            for (int c = 0; c < 4; ++c) {
                const float* kp = kernels + (((s * HEADS) + c) * NH + h) * 32 + 2 * p;
                o[c] = packh(kp[0] * sc * inv[c], kp[1] * sc * inv[c]);
            }
            wtab[h * NPAIR + pp] = o;
        }
    }
}

// ---------------------------------------------------------------------------
// Main conv kernel.  Grid: (4, 256, 16), 256 threads.
// Per thread: 4 consecutive t (A=4*tid), all 4 heads.
// Z_r[m] = pack(W_r[m] lo, W_r[m-r] hi);  dot2(Z_r[i], wpair) covers 2 taps.
// dot2 via explicit v_dot2_f32_f16 asm (ISA semantics, no builtin lowering).
// ---------------------------------------------------------------------------
__global__ __launch_bounds__(256) void conv_kernel(
    const float* __restrict__ x,
    const u32x4* __restrict__ wtab,
    const float* __restrict__ D,
    float*       __restrict__ out)
{
    __shared__ __align__(16) float    xs_raw[32 + 2048];   // 32-elem zero pad
    __shared__ __align__(16) unsigned Z1 [2048];
    __shared__ __align__(16) unsigned Z2 [2048];
    __shared__ __align__(16) unsigned Z4 [2048];
    __shared__ __align__(16) unsigned Z8 [2048];
    __shared__ __align__(16) unsigned Z16[2048];

    float* xs = xs_raw + 32;

    const int tile = blockIdx.x;
    const int h    = blockIdx.y;
    const int b    = blockIdx.z;
    const int tid  = threadIdx.x;
    const int t0   = tile * TT;

    const float* xrow = x + ((size_t)(b * NH + h)) * LEN;

    // ---- pad + stage x (local m in [0,2048), global g = t0-512+m) ----
    if (tid < 32) xs_raw[tid] = 0.f;
    {
        const int m0 = 8 * tid;
        const int g0 = t0 - 512 + m0;
        if (g0 >= 0 && g0 + 7 < LEN) {
            *(f32x4*)&xs[m0]     = *(const f32x4*)(xrow + g0);
            *(f32x4*)&xs[m0 + 4] = *(const f32x4*)(xrow + g0 + 4);
        } else {
            #pragma unroll
            for (int e = 0; e < 8; ++e) {
                const int g = g0 + e;
                xs[m0 + e] = (g >= 0 && g < LEN) ? xrow[g] : 0.f;
            }
        }
    }
    __syncthreads();

    // ---- in-place window-sum chain + f16 pair packing ----
    {
        const int base = 8 * tid - 32;
        const int m0   = 8 * tid;
        float v[40];
        #pragma unroll
        for (int j = 0; j < 40; j += 4) {
            const f32x4 t = *(const f32x4*)&xs[base + j];
            v[j] = t.x; v[j + 1] = t.y; v[j + 2] = t.z; v[j + 3] = t.w;
        }

        unsigned z[8];
        #pragma unroll
        for (int e = 0; e < 8; ++e) z[e] = packh(v[32 + e], v[31 + e]);
        *(u32x4*)&Z1[m0]     = (u32x4){z[0], z[1], z[2], z[3]};
        *(u32x4*)&Z1[m0 + 4] = (u32x4){z[4], z[5], z[6], z[7]};

        #pragma unroll
        for (int j = 39; j >= 2; --j) v[j] += v[j - 1];      // -> W2
        #pragma unroll
        for (int e = 0; e < 8; ++e) z[e] = packh(v[32 + e], v[30 + e]);
        *(u32x4*)&Z2[m0]     = (u32x4){z[0], z[1], z[2], z[3]};
        *(u32x4*)&Z2[m0 + 4] = (u32x4){z[4], z[5], z[6], z[7]};

        #pragma unroll
        for (int j = 39; j >= 4; --j) v[j] += v[j - 2];      // -> W4
        #pragma unroll
        for (int e = 0; e < 8; ++e) z[e] = packh(v[32 + e], v[28 + e]);
        *(u32x4*)&Z4[m0]     = (u32x4){z[0], z[1], z[2], z[3]};
        *(u32x4*)&Z4[m0 + 4] = (u32x4){z[4], z[5], z[6], z[7]};

        #pragma unroll
        for (int j = 39; j >= 8; --j) v[j] += v[j - 4];      // -> W8
        #pragma unroll
        for (int e = 0; e < 8; ++e) z[e] = packh(v[32 + e], v[24 + e]);
        *(u32x4*)&Z8[m0]     = (u32x4){z[0], z[1], z[2], z[3]};
        *(u32x4*)&Z8[m0 + 4] = (u32x4){z[4], z[5], z[6], z[7]};

        #pragma unroll
        for (int j = 39; j >= 16; --j) v[j] += v[j - 8];     // -> W16
        #pragma unroll
        for (int e = 0; e < 8; ++e) z[e] = packh(v[32 + e], v[16 + e]);
        *(u32x4*)&Z16[m0]     = (u32x4){z[0], z[1], z[2], z[3]};
        *(u32x4*)&Z16[m0 + 4] = (u32x4){z[4], z[5], z[6], z[7]};
    }
    __syncthreads();

    const int A = 4 * tid;
    float acc[4][4];
    #pragma unroll
    for (int c = 0; c < 4; ++c)
        #pragma unroll
        for (int d = 0; d < 4; ++d) acc[c][d] = 0.f;

    const u32x4* wq = wtab + h * NPAIR;

// D.f32 = Z.f16[0]*W.f16[0] + Z.f16[1]*W.f16[1] + ACC  (ISA VOP3P)
#define DOT_ASM(ACC, Z, WW) \
    asm("v_dot2_f32_f16 %0, %1, %2, %0" : "+v"(ACC) : "v"(Z), "s"(WW))

#define DOT1(ZD, W, DIDX) do {                 \
        const unsigned _z = (ZD);              \
        DOT_ASM(acc[0][DIDX], _z, (W).x);      \
        DOT_ASM(acc[1][DIDX], _z, (W).y);      \
        DOT_ASM(acc[2][DIDX], _z, (W).z);      \
        DOT_ASM(acc[3][DIDX], _z, (W).w);      \
    } while (0)

    // ---- scales 0+1 (r=1): pairs 0..31, base 1024 ----
    #pragma unroll 4
    for (int p = 0; p < 32; ++p) {
        const int i = A + 1024 - 2 * p;
        const u32x2 zl = *(const u32x2*)&Z1[i];
        const u32x2 zh = *(const u32x2*)&Z1[i + 2];
        const u32x4 w  = wq[p];
        DOT1(zl.x, w, 0); DOT1(zl.y, w, 1); DOT1(zh.x, w, 2); DOT1(zh.y, w, 3);
    }
    // ---- scale 2 (r=2): pairs 32..47, base 960 ----
    #pragma unroll 4
    for (int p = 0; p < 16; ++p) {
        const int i = A + 960 - 4 * p;
        const u32x4 z = *(const u32x4*)&Z2[i];
        const u32x4 w = wq[32 + p];
        DOT1(z.x, w, 0); DOT1(z.y, w, 1); DOT1(z.z, w, 2); DOT1(z.w, w, 3);
    }
    // ---- scale 3 (r=4): pairs 48..63, base 896 ----
    #pragma unroll 4
    for (int p = 0; p < 16; ++p) {
        const int i = A + 896 - 8 * p;
        const u32x4 z = *(const u32x4*)&Z4[i];
        const u32x4 w = wq[48 + p];
        DOT1(z.x, w, 0); DOT1(z.y, w, 1); DOT1(z.z, w, 2); DOT1(z.w, w, 3);
    }
    // ---- scale 4 (r=8): pairs 64..79, base 768 ----
    #pragma unroll 4
    for (int p = 0; p < 16; ++p) {
        const int i = A + 768 - 16 * p;
        const u32x4 z = *(const u32x4*)&Z8[i];
        const u32x4 w = wq[64 + p];
        DOT1(z.x, w, 0); DOT1(z.y, w, 1); DOT1(z.z, w, 2); DOT1(z.w, w, 3);
    }
    // ---- scale 5 (r=16): pairs 80..95, base 512 ----
    #pragma unroll 4
    for (int p = 0; p < 16; ++p) {
        const int i = A + 512 - 32 * p;
        const u32x4 z = *(const u32x4*)&Z16[i];
        const u32x4 w = wq[80 + p];
        DOT1(z.x, w, 0); DOT1(z.y, w, 1); DOT1(z.z, w, 2); DOT1(z.w, w, 3);
    }
#undef DOT1
#undef DOT_ASM

    // ---- skip connection + store ----
    const f32x4 xv = *(const f32x4*)&xs[A + 512];
    const float d0 = D[0 * NH + h];
    const float d1 = D[1 * NH + h];
    const float d2 = D[2 * NH + h];
    const float d3 = D[3 * NH + h];

    const size_t obase = ((size_t)b * (NH * HEADS) + (size_t)h * HEADS) * LEN
                       + (size_t)t0 + (size_t)A;

    f32x4 o;
    o = (f32x4){acc[0][0], acc[0][1], acc[0][2], acc[0][3]} + xv * d0;
    *reinterpret_cast<f32x4*>(out + obase + 0 * LEN) = o;
    o = (f32x4){acc[1][0], acc[1][1], acc[1][2], acc[1][3]} + xv * d1;
    *reinterpret_cast<f32x4*>(out + obase + 1 * LEN) = o;
    o = (f32x4){acc[2][0], acc[2][1], acc[2][2], acc[2][3]} + xv * d2;
    *reinterpret_cast<f32x4*>(out + obase + 2 * LEN) = o;
    o = (f32x4){acc[3][0], acc[3][1], acc[3][2], acc[3][3]} + xv * d3;
    *reinterpret_cast<f32x4*>(out + obase + 3 * LEN) = o;
}

extern "C" void kernel_launch(void* const* d_in, const int* in_sizes, int n_in,
                              void* d_out, int out_size, void* d_ws, size_t ws_size,
                              hipStream_t stream)
{
    const float* x       = (const float*)d_in[0];
    const float* kernels = (const float*)d_in[1];
    const float* D       = (const float*)d_in[2];
    float*       out     = (float*)d_out;
    u32x4*       wtab    = (u32x4*)d_ws;   // 256*96*16 B = 384 KiB

    build_wgt_kernel<<<256, 64, 0, stream>>>(kernels, wtab);
    conv_kernel<<<dim3(LEN / TT, NH, NB), 256, 0, stream>>>(x, wtab, D, out);
}

// Round 7
// 251.944 us; speedup vs baseline: 1.6379x; 1.0271x over previous
//
#include <hip/hip_runtime.h>

#define HEADS 4
#define NH    256
#define LEN   4096
#define NB    16
#define TT    1024
#define NSUB  4

typedef float     f32x4 __attribute__((ext_vector_type(4)));
typedef float     f32x2 __attribute__((ext_vector_type(2)));
typedef _Float16  f16x8 __attribute__((ext_vector_type(8)));
typedef unsigned  u32x2 __attribute__((ext_vector_type(2)));
typedef unsigned  u32x4 __attribute__((ext_vector_type(4)));

__device__ __forceinline__ unsigned packh(float a, float b) {
    union { _Float16 h[2]; unsigned u; } z;
    z.h[0] = (_Float16)a; z.h[1] = (_Float16)b;
    return z.u;
}
__device__ __forceinline__ unsigned short h16u(float a) {
    union { _Float16 h; unsigned short u; } z;
    z.h = (_Float16)a; return z.u;
}

// ---------------------------------------------------------------------------
// Weight table for A-fragments: per (h, c, unit): Prev[y], y in [0,128):
//   Prev[y] = w_u[95 - y] (f16, normalized), zero outside the unit's tap range.
// Units: 0 = merged scales 0+1 (J=64, w01[j] = j<32 ? w0[j] : w1[j-32]),
//        u>=1 -> scale u+1 (J=32).  A[delta,k] = w[delta + J - k].
// ---------------------------------------------------------------------------
__global__ __launch_bounds__(64) void build_wgt_kernel(
    const float* __restrict__ kernels, unsigned short* __restrict__ wtab)
{
    const int h    = blockIdx.x;
    const int lane = threadIdx.x;

    float ssum[4] = {0.f, 0.f, 0.f, 0.f};
    #pragma unroll
    for (int q = 0; q < 3; ++q) {
        const int tap = lane + q * 64;
        const int i = tap >> 5;
        const int j = tap & 31;
        const float scale = (float)(1 << (5 - i));
        const float repf  = (float)(i == 0 ? 1 : (1 << (i - 1)));
        #pragma unroll
        for (int c = 0; c < 4; ++c) {
            const float kv = kernels[(((i * HEADS) + c) * NH + h) * 32 + j];
            const float v  = kv * scale;
            ssum[c] += v * v * repf;
        }
    }
    #pragma unroll
    for (int off = 32; off > 0; off >>= 1) {
        #pragma unroll
        for (int c = 0; c < 4; ++c) ssum[c] += __shfl_xor(ssum[c], off);
    }
    float inv[4];
    #pragma unroll
    for (int c = 0; c < 4; ++c) inv[c] = 1.0f / sqrtf(ssum[c]);

    // fill 4c * 5u * 128 = 2560 entries
    for (int it = 0; it < 40; ++it) {
        const int idx = it * 64 + lane;
        const int c   = idx / 640;
        const int rem = idx - c * 640;
        const int u   = rem >> 7;
        const int y   = rem & 127;
        const int j   = 95 - y;
        const int J   = (u == 0) ? 64 : 32;
        float val = 0.f;
        if (j >= 0 && j < J) {
            int s, tp;
            if (u == 0) { s = (j < 32) ? 0 : 1; tp = j & 31; }
            else        { s = u + 1;            tp = j;      }
            val = kernels[((s * HEADS + c) * NH + h) * 32 + tp]
                  * (float)(1 << (5 - s)) * inv[c];
        }
        wtab[((h * 4 + c) * 5 + u) * 128 + y] = h16u(val);
    }
}

// ---------------------------------------------------------------------------
// MFMA conv kernel.  Grid (2 cpair, 256 h, 16 b), 256 threads (4 waves).
// Per subtile (1024 t): build phase-striped windowed-sum arrays G_r (f16),
// then per wave (owns 16 output cols = 256 consecutive t): banded-Toeplitz
// MFMAs per unit, raw-D via LDS overlay, structured gather + skip + store.
// ---------------------------------------------------------------------------
// G element offsets (f16 units)
#define G1O   0
#define G2O   2080
#define G4O   4128
#define G8O   6176
#define G16O  8224
#define GTOT  10272

#define MFMA16(acc, a, bb) \
    (acc) = __builtin_amdgcn_mfma_f32_16x16x32_f16((a), (bb), (acc), 0, 0, 0)

__global__ __launch_bounds__(256, 2) void conv_kernel(
    const float*           __restrict__ x,
    const unsigned short*  __restrict__ wtab,
    const float*           __restrict__ Dp,
    float*                 __restrict__ out)
{
    __shared__ __align__(16) unsigned short G[GTOT];

    const int cpair = blockIdx.x;
    const int h     = blockIdx.y;
    const int b     = blockIdx.z;
    const int tid   = threadIdx.x;
    const int w     = tid >> 6;
    const int lane  = tid & 63;
    const int dd    = lane & 15;     // delta / col index within fragments
    const int qq    = lane >> 4;     // k-chunk group

    const float* xrow = x + ((size_t)(b * NH + h)) * LEN;

    // ---- A-fragments: 22 x f16x8, built from global ushort loads ----
    f16x8 AF[22];
    #pragma unroll
    for (int cc = 0; cc < 2; ++cc) {
        const int c = cpair * 2 + cc;
        const unsigned short* wpc = wtab + (size_t)((h * 4 + c) * 5) * 128;
        #pragma unroll
        for (int u = 0; u < 5; ++u) {
            const int J   = (u == 0) ? 64 : 32;
            const int nM  = (u == 0) ? 3 : 2;
            const int bse = (u == 0) ? 0 : (2 * u + 1);
            const unsigned short* wp = wpc + u * 128;
            #pragma unroll
            for (int m = 0; m < 3; ++m) {
                if (m < nM) {
                    const int y0 = 95 - dd - J + 32 * m + 8 * qq;
                    u32x4 dw;
                    #pragma unroll
                    for (int d = 0; d < 4; ++d)
                        dw[d] = (unsigned)wp[y0 + 2 * d]
                              | ((unsigned)wp[y0 + 2 * d + 1] << 16);
                    AF[cc * 11 + bse + m] = __builtin_bit_cast(f16x8, dw);
                }
            }
        }
    }

    // ---- B-fragment base element addresses per unit ----
    const int kap = 16 * w + dd;     // global col
    const int e0 = G1O  + 16 * kap + 960 + 8 * qq;
    const int e1 = G2O  + (kap & 1)  * 1024 + 16 * (kap >> 1) + 448 + 8 * qq;
    const int e2 = G4O  + (kap & 3)  * 512  + 16 * (kap >> 2) + 192 + 8 * qq;
    const int e3 = G8O  + (kap & 7)  * 256  + 16 * (kap >> 3) + 64  + 8 * qq;
    const int e4 = G16O + (kap & 15) * 128  + 16 * (kap >> 4)       + 8 * qq;

    for (int st = 0; st < NSUB; ++st) {
        const int t0s = st * TT;
        __syncthreads();   // protect G/D region reuse across subtiles

        // ---- prefix chain (register doubling) + striped f16 G-writes ----
        {
            const int m0 = 8 * tid;
            const int bg = t0s - 544 + m0;     // global index of v[0]
            float v[40];
            #pragma unroll
            for (int blk = 0; blk < 10; ++blk) {
                const int g = bg + 4 * blk;
                f32x4 t;
                if (g >= 0 && g + 3 < LEN) {
                    t = *(const f32x4*)(xrow + g);
                } else {
                    #pragma unroll
                    for (int e = 0; e < 4; ++e) {
                        const int gg = g + e;
                        t[e] = (gg >= 0 && gg < LEN) ? xrow[gg] : 0.f;
                    }
                }
                v[4 * blk] = t.x; v[4 * blk + 1] = t.y;
                v[4 * blk + 2] = t.z; v[4 * blk + 3] = t.w;
            }
            // G1 = x (f16)
            {
                u32x4 px;
                px[0] = packh(v[32], v[33]); px[1] = packh(v[34], v[35]);
                px[2] = packh(v[36], v[37]); px[3] = packh(v[38], v[39]);
                *(u32x4*)&G[G1O + m0] = px;
            }
            if (tid < 4) *(u32x4*)&G[G1O + 2048 + 8 * tid] = (u32x4){0, 0, 0, 0};

            #pragma unroll
            for (int j = 39; j >= 2; --j) v[j] += v[j - 1];      // W2
            #pragma unroll
            for (int ph = 0; ph < 2; ++ph) {
                u32x2 pw;
                pw.x = packh(v[32 + ph], v[34 + ph]);
                pw.y = packh(v[36 + ph], v[38 + ph]);
                *(u32x2*)&G[G2O + ph * 1024 + (m0 >> 1)] = pw;
            }
            #pragma unroll
            for (int j = 39; j >= 4; --j) v[j] += v[j - 2];      // W4
            #pragma unroll
            for (int ph = 0; ph < 4; ++ph)
                *(unsigned*)&G[G4O + ph * 512 + (m0 >> 2)] =
                    packh(v[32 + ph], v[36 + ph]);
            #pragma unroll
            for (int j = 39; j >= 8; --j) v[j] += v[j - 4];      // W8
            #pragma unroll
            for (int e = 0; e < 8; ++e)
                G[G8O + e * 256 + tid] = h16u(v[32 + e]);
            #pragma unroll
            for (int j = 39; j >= 16; --j) v[j] += v[j - 8];     // W16
            #pragma unroll
            for (int e = 0; e < 8; ++e)
                G[G16O + ((m0 & 8) + e) * 128 + (m0 >> 4)] = h16u(v[32 + e]);
        }
        __syncthreads();

        // ---- MFMA phase ----
        f32x4 DA[2][5];
        #pragma unroll
        for (int cc = 0; cc < 2; ++cc)
            #pragma unroll
            for (int u = 0; u < 5; ++u) DA[cc][u] = (f32x4){0.f, 0.f, 0.f, 0.f};

        {   // unit 0 (r=1, K=96)
            const f16x8 b0 = *(const f16x8*)&G[e0];
            const f16x8 b1 = *(const f16x8*)&G[e0 + 32];
            const f16x8 b2 = *(const f16x8*)&G[e0 + 64];
            MFMA16(DA[0][0], AF[0],  b0); MFMA16(DA[0][0], AF[1],  b1);
            MFMA16(DA[0][0], AF[2],  b2);
            MFMA16(DA[1][0], AF[11], b0); MFMA16(DA[1][0], AF[12], b1);
            MFMA16(DA[1][0], AF[13], b2);
        }
        {   // unit 1 (r=2)
            const f16x8 b0 = *(const f16x8*)&G[e1];
            const f16x8 b1 = *(const f16x8*)&G[e1 + 32];
            MFMA16(DA[0][1], AF[3],  b0); MFMA16(DA[0][1], AF[4],  b1);
            MFMA16(DA[1][1], AF[14], b0); MFMA16(DA[1][1], AF[15], b1);
        }
        {   // unit 2 (r=4)
            const f16x8 b0 = *(const f16x8*)&G[e2];
            const f16x8 b1 = *(const f16x8*)&G[e2 + 32];
            MFMA16(DA[0][2], AF[5],  b0); MFMA16(DA[0][2], AF[6],  b1);
            MFMA16(DA[1][2], AF[16], b0); MFMA16(DA[1][2], AF[17], b1);
        }
        {   // unit 3 (r=8)
            const f16x8 b0 = *(const f16x8*)&G[e3];
            const f16x8 b1 = *(const f16x8*)&G[e3 + 32];
            MFMA16(DA[0][3], AF[7],  b0); MFMA16(DA[0][3], AF[8],  b1);
            MFMA16(DA[1][3], AF[18], b0); MFMA16(DA[1][3], AF[19], b1);
        }
        {   // unit 4 (r=16)
            const f16x8 b0 = *(const f16x8*)&G[e4];
            const f16x8 b1 = *(const f16x8*)&G[e4 + 32];
            MFMA16(DA[0][4], AF[9],  b0); MFMA16(DA[0][4], AF[10], b1);
            MFMA16(DA[1][4], AF[20], b0); MFMA16(DA[1][4], AF[21], b1);
        }
        __syncthreads();   // all B-reads done; G region becomes D-raw scratch

        // ---- D-raw write + gather + skip + store (per c, wave-private) ----
        float* DR = (float*)G;
        const int t00 = 4 * lane;          // within-wave local t base
        #pragma unroll
        for (int cc = 0; cc < 2; ++cc) {
            #pragma unroll
            for (int u = 0; u < 5; ++u)
                *(f32x4*)&DR[((w * 5 + u) * 64 + lane) * 4] = DA[cc][u];

            f32x4 acc;
            {   // unit0: r=1, t = 16*col + delta
                const int sL = (lane >> 2) + 16 * (lane & 3);
                acc = *(const f32x4*)&DR[((w * 5 + 0) * 64 + sL) * 4];
            }
            {   // unit1: r=2
                const int da = (2 * lane) & 15;          // even
                const int uu = lane >> 3;
                const int L  = 2 * uu + 16 * (da >> 2);
                const int bi = ((w * 5 + 1) * 64 + L) * 4 + (da & 3);
                const f32x2 P = *(const f32x2*)&DR[bi];
                const f32x2 Q = *(const f32x2*)&DR[bi + 4];
                acc[0] += P.x; acc[1] += Q.x; acc[2] += P.y; acc[3] += Q.y;
            }
            {   // unit2: r=4
                const int de = lane & 15;
                const int uu = lane >> 4;
                const int L0 = 4 * uu + 16 * (de >> 2);
                const int bi = ((w * 5 + 2) * 64 + L0) * 4 + (de & 3);
                #pragma unroll
                for (int e = 0; e < 4; ++e) acc[e] += DR[bi + 4 * e];
            }
            {   // unit3: r=8
                const int de = (lane >> 1) & 15;
                const int uu = lane >> 5;
                const int L0 = 8 * uu + 4 * (lane & 1) + 16 * (de >> 2);
                const int bi = ((w * 5 + 3) * 64 + L0) * 4 + (de & 3);
                #pragma unroll
                for (int e = 0; e < 4; ++e) acc[e] += DR[bi + 4 * e];
            }
            {   // unit4: r=16
                const int de = (lane >> 2) & 15;
                const int L0 = 4 * (lane & 3) + 16 * (de >> 2);
                const int bi = ((w * 5 + 4) * 64 + L0) * 4 + (de & 3);
                #pragma unroll
                for (int e = 0; e < 4; ++e) acc[e] += DR[bi + 4 * e];
            }

            const int c  = cpair * 2 + cc;
            const int gt = t0s + 256 * w + t00;
            const f32x4 xv = *(const f32x4*)(xrow + gt);
            acc += xv * Dp[c * NH + h];
            *(f32x4*)(out + ((size_t)(b * NH + h) * 4 + c) * LEN + gt) = acc;
        }
    }
}

extern "C" void kernel_launch(void* const* d_in, const int* in_sizes, int n_in,
                              void* d_out, int out_size, void* d_ws, size_t ws_size,
                              hipStream_t stream)
{
    const float* x       = (const float*)d_in[0];
    const float* kernels = (const float*)d_in[1];
    const float* D       = (const float*)d_in[2];
    float*       out     = (float*)d_out;
    unsigned short* wtab = (unsigned short*)d_ws;   // 256*4*5*128*2B = 1.31 MB

    build_wgt_kernel<<<256, 64, 0, stream>>>(kernels, wtab);
    conv_kernel<<<dim3(2, NH, NB), 256, 0, stream>>>(x, wtab, D, out);
}